// Round 4
// baseline (759.253 us; speedup 1.0000x reference)
//
#include <hip/hip_runtime.h>
#include <hip/hip_bf16.h>

#define DD 768
#define NPATCH 576
#define BMR 64            // mem rows per chunk
#define NSLAB 24          // K slabs of 32
#define EPSF 1e-6f
#define NRB 384           // row-block groups (grid = 2 * NRB = 768 = 3 blocks/CU)

typedef short bf16x8 __attribute__((ext_vector_type(8)));
typedef float f32x4 __attribute__((ext_vector_type(4)));

__device__ __forceinline__ unsigned short f2bf(float x) {
  __hip_bfloat16 h = __float2bfloat16(x);
  return __builtin_bit_cast(unsigned short, h);
}

// ---------------- kernel 1: patch row norms ----------------
__global__ __launch_bounds__(256) void k_norm(const float* __restrict__ pf,
                                              float* __restrict__ invn) {
  int row = blockIdx.x;          // 576
  int t = threadIdx.x;
  const float* src = pf + (size_t)row * DD;
  float v0 = src[t], v1 = src[t + 256], v2 = src[t + 512];
  float ss = v0 * v0 + v1 * v1 + v2 * v2;
#pragma unroll
  for (int m = 1; m < 64; m <<= 1) ss += __shfl_xor(ss, m, 64);
  __shared__ float wss[4];
  if ((t & 63) == 0) wss[t >> 6] = ss;
  __syncthreads();
  if (t == 0) {
    float tot = wss[0] + wss[1] + wss[2] + wss[3];
    invn[row] = 1.0f / (sqrtf(tot) + EPSF);
  }
}

// ---------------- kernel 2: pack F into slab-fragment layout ----------------
// Fws[ks][ptg][slot][8] bf16: patch = ptg*16 + (slot&15), k = ks*32 + (slot>>4)*8 + j
__global__ __launch_bounds__(256) void k_pack(const float* __restrict__ pf,
                                              const float* __restrict__ invn,
                                              unsigned short* __restrict__ Fws) {
  int bid = blockIdx.x;          // 864 = 24 ks * 36 ptg
  int ks = bid / 36, ptg = bid % 36;
  int t = threadIdx.x;
  int i = t * 2;                 // short index in region [0,512)
  int s = i >> 3, j = i & 7;
  int p = ptg * 16 + (s & 15);
  int k = ks * 32 + (s >> 4) * 8 + j;
  float sc = invn[p];
  float a0 = pf[(size_t)p * DD + k] * sc;
  float a1 = pf[(size_t)p * DD + k + 1] * sc;
  unsigned int outw = (unsigned int)f2bf(a0) | ((unsigned int)f2bf(a1) << 16);
  ((unsigned int*)Fws)[(size_t)bid * 256 + t] = outw;
}

// ---------------- kernel 3: main MFMA kernel ----------------
// 256 threads = 4 waves: pw = w&1 (9 patch-tiles each), rw = w>>1 (2 row-tiles each)
// A-fragments read directly from L2-resident Fws; B double-buffered in 4KB LDS slabs.
__global__ __launch_bounds__(256, 3) void k_main(const unsigned short* __restrict__ Fws,
                                                 const float* __restrict__ mem,
                                                 float* __restrict__ partial,
                                                 int M, int nchunk) {
  __shared__ __align__(16) unsigned short Bs[2][2048];   // 2 x 4KB bf16 slab
  __shared__ float smin[2][288];
  __shared__ float ssq[BMR];

  int t = threadIdx.x;
  int l = t & 63, l15 = l & 15, lhi = l >> 4;
  int w = t >> 6, pw = w & 1, rw = w >> 1;
  int c = blockIdx.x & 1, rb = blockIdx.x >> 1;
  int srow = t >> 2, sq = t & 3;      // staging: row 0..63, k-seg 0..3

  for (int i = t; i < 2 * 288; i += 256) ((float*)smin)[i] = 1e30f;

  // A fragment base: tiles (c*18 + pw*9 + p), lane slot (lhi*16+l15)
  const unsigned short* Abase =
      Fws + (size_t)(c * 18 + pw * 9) * 512 + (size_t)(lhi * 16 + l15) * 8;

  // B read byte-offsets (swizzled) for my two row-tiles
  int rbyte0, rbyte1;
  {
    int sw = ((l15 & 7) << 4);
    rbyte0 = (rw * 2 + 0) * 1024 + ((l15 * 64 + lhi * 16) ^ sw);
    rbyte1 = (rw * 2 + 1) * 1024 + ((l15 * 64 + lhi * 16) ^ sw);
  }
  // B write byte-offset (same swizzle): row srow, k-seg sq
  int wl15 = srow & 15;
  int wbyte = (srow >> 4) * 1024 + ((wl15 * 64 + sq * 16) ^ ((wl15 & 7) << 4));

#pragma unroll 1
  for (int chunk = rb; chunk < nchunk; chunk += NRB) {
    int grow = chunk * BMR + srow;
    if (grow > M - 1) grow = M - 1;
    const float* gsrc = mem + (size_t)grow * DD + sq * 8;
    float ssr = 0.f;

    // ---- prologue: stage slab 0 into Bs[0] ----
    {
      float4 v0 = *(const float4*)(gsrc);
      float4 v1 = *(const float4*)(gsrc + 4);
      ssr += v0.x * v0.x + v0.y * v0.y + v0.z * v0.z + v0.w * v0.w +
             v1.x * v1.x + v1.y * v1.y + v1.z * v1.z + v1.w * v1.w;
      uint4 bw;
      bw.x = (unsigned int)f2bf(v0.x) | ((unsigned int)f2bf(v0.y) << 16);
      bw.y = (unsigned int)f2bf(v0.z) | ((unsigned int)f2bf(v0.w) << 16);
      bw.z = (unsigned int)f2bf(v1.x) | ((unsigned int)f2bf(v1.y) << 16);
      bw.w = (unsigned int)f2bf(v1.z) | ((unsigned int)f2bf(v1.w) << 16);
      *(uint4*)((char*)Bs[0] + wbyte) = bw;
    }
    __syncthreads();

    f32x4 acc[9][2];
#pragma unroll
    for (int p = 0; p < 9; ++p) {
      f32x4 z = {0.f, 0.f, 0.f, 0.f};
      acc[p][0] = z;
      acc[p][1] = z;
    }

#pragma unroll 1
    for (int ks = 0; ks < NSLAB; ++ks) {
      int cur = ks & 1;
      bool st = ks < NSLAB - 1;
      float4 v0, v1;
      if (st) {  // T14: issue next-slab B loads before compute
        const float* g = gsrc + (ks + 1) * 32;
        v0 = *(const float4*)g;
        v1 = *(const float4*)(g + 4);
      }
      // compute on cur: 2 LDS B-frags + 9 global A-frags -> 18 MFMA
      bf16x8 b0 = *(const bf16x8*)((const char*)Bs[cur] + rbyte0);
      bf16x8 b1 = *(const bf16x8*)((const char*)Bs[cur] + rbyte1);
      const unsigned short* Ak = Abase + (size_t)ks * (36 * 512);
#pragma unroll
      for (int p = 0; p < 9; ++p) {
        bf16x8 a = *(const bf16x8*)(Ak + p * 512);
        acc[p][0] = __builtin_amdgcn_mfma_f32_16x16x32_bf16(a, b0, acc[p][0], 0, 0, 0);
        acc[p][1] = __builtin_amdgcn_mfma_f32_16x16x32_bf16(a, b1, acc[p][1], 0, 0, 0);
      }
      if (st) {  // convert + write next slab
        ssr += v0.x * v0.x + v0.y * v0.y + v0.z * v0.z + v0.w * v0.w +
               v1.x * v1.x + v1.y * v1.y + v1.z * v1.z + v1.w * v1.w;
        uint4 bw;
        bw.x = (unsigned int)f2bf(v0.x) | ((unsigned int)f2bf(v0.y) << 16);
        bw.y = (unsigned int)f2bf(v0.z) | ((unsigned int)f2bf(v0.w) << 16);
        bw.z = (unsigned int)f2bf(v1.x) | ((unsigned int)f2bf(v1.y) << 16);
        bw.w = (unsigned int)f2bf(v1.z) | ((unsigned int)f2bf(v1.w) << 16);
        *(uint4*)((char*)Bs[cur ^ 1] + wbyte) = bw;
      }
      __syncthreads();
    }

    // ---- ssq: reduce over the 4 k-seg threads per row (in-wave) ----
    float s2 = ssr + __shfl_xor(ssr, 1, 64);
    s2 += __shfl_xor(s2, 2, 64);
    if (sq == 0) ssq[srow] = s2;
    __syncthreads();

    // ---- epilogue: dist + min over this chunk's 64 rows ----
    float inv0, inv1;
    bool ok0, ok1;
    {
      int rl0 = (rw * 2 + 0) * 16 + l15;
      int rl1 = (rw * 2 + 1) * 16 + l15;
      inv0 = 1.0f / (sqrtf(ssq[rl0]) + EPSF);
      inv1 = 1.0f / (sqrtf(ssq[rl1]) + EPSF);
      ok0 = (chunk * BMR + rl0) < M;
      ok1 = (chunk * BMR + rl1) < M;
    }
#pragma unroll
    for (int p = 0; p < 9; ++p) {
#pragma unroll
      for (int q = 0; q < 4; ++q) {
        float e0 = ok0 ? (1.0f - acc[p][0][q] * inv0) : 1e30f;
        float e1 = ok1 ? (1.0f - acc[p][1][q] * inv1) : 1e30f;
        float d = fminf(e0, e1);
        d = fminf(d, __shfl_xor(d, 1, 64));
        d = fminf(d, __shfl_xor(d, 2, 64));
        d = fminf(d, __shfl_xor(d, 4, 64));
        d = fminf(d, __shfl_xor(d, 8, 64));
        if (l15 == 0) {
          int pl = (pw * 9 + p) * 16 + lhi * 4 + q;
          smin[rw][pl] = fminf(smin[rw][pl], d);
        }
      }
    }
    __syncthreads();   // smin/ssq settled before next chunk
  }

  for (int i = t; i < 288; i += 256)
    partial[(size_t)rb * NPATCH + c * 288 + i] = fminf(smin[0][i], smin[1][i]);
}

// ---------------- kernel 4: min over partials -> patch_scores ----------------
__global__ __launch_bounds__(256) void k_colmin(const float* __restrict__ partial,
                                                float* __restrict__ out, int nb) {
  int p = blockIdx.x;   // 576
  int t = threadIdx.x;
  float v = 1e30f;
  for (int b = t; b < nb; b += 256) v = fminf(v, partial[(size_t)b * NPATCH + p]);
#pragma unroll
  for (int m = 1; m < 64; m <<= 1) v = fminf(v, __shfl_xor(v, m, 64));
  __shared__ float wmin[4];
  if ((t & 63) == 0) wmin[t >> 6] = v;
  __syncthreads();
  if (t == 0) out[p] = fminf(fminf(wmin[0], wmin[1]), fminf(wmin[2], wmin[3]));
}

// ---------------- kernel 5: top-k mean -> image score ----------------
__global__ __launch_bounds__(256) void k_topk(float* __restrict__ out,
                                              const int* __restrict__ topk_p) {
  __shared__ float vals[NPATCH];
  __shared__ float wv[4];
  __shared__ int wi[4];
  __shared__ float ssum;
  int t = threadIdx.x;
  for (int p = t; p < NPATCH; p += 256) vals[p] = out[p];
  if (t == 0) ssum = 0.f;
  int k = topk_p[0];
  if (k > NPATCH) k = NPATCH;
  if (k < 1) k = 1;
  __syncthreads();
  for (int it = 0; it < k; ++it) {
    float bv = -1e30f;
    int bi = 0;
    for (int p = t; p < NPATCH; p += 256) {
      float x = vals[p];
      if (x > bv) { bv = x; bi = p; }
    }
#pragma unroll
    for (int m = 1; m < 64; m <<= 1) {
      float ov = __shfl_xor(bv, m, 64);
      int oi = __shfl_xor(bi, m, 64);
      if (ov > bv || (ov == bv && oi < bi)) { bv = ov; bi = oi; }
    }
    if ((t & 63) == 0) { wv[t >> 6] = bv; wi[t >> 6] = bi; }
    __syncthreads();
    if (t == 0) {
      float fbv = wv[0]; int fbi = wi[0];
      for (int q = 1; q < 4; ++q)
        if (wv[q] > fbv || (wv[q] == fbv && wi[q] < fbi)) { fbv = wv[q]; fbi = wi[q]; }
      ssum += fbv;
      vals[fbi] = -1e30f;
    }
    __syncthreads();
  }
  if (t == 0) out[NPATCH] = ssum / (float)k;
}

extern "C" void kernel_launch(void* const* d_in, const int* in_sizes, int n_in,
                              void* d_out, int out_size, void* d_ws, size_t ws_size,
                              hipStream_t stream) {
  const float* pf = (const float*)d_in[0];
  const float* mem = (const float*)d_in[1];
  const int* topk = (const int*)d_in[2];
  float* out = (float*)d_out;
  int M = in_sizes[1] / DD;                      // 200000
  int nchunk = (M + BMR - 1) / BMR;              // 3125

  // ws layout: Fws (24*36*512 shorts = 884736B) | invn (576*4) | partial (384*576*4)
  unsigned short* Fws = (unsigned short*)d_ws;
  float* invn = (float*)((char*)d_ws + 884736);
  float* partial = (float*)((char*)d_ws + 884736 + 2304);

  k_norm<<<NPATCH, 256, 0, stream>>>(pf, invn);
  k_pack<<<864, 256, 0, stream>>>(pf, invn, Fws);
  k_main<<<2 * NRB, 256, 0, stream>>>(Fws, mem, partial, M, nchunk);
  k_colmin<<<NPATCH, 256, 0, stream>>>(partial, out, NRB);
  k_topk<<<1, 256, 0, stream>>>(out, topk);
}

// Round 5
// 370.528 us; speedup vs baseline: 2.0491x; 2.0491x over previous
//
#include <hip/hip_runtime.h>
#include <hip/hip_bf16.h>

#define DD 768
#define NPATCH 576
#define BMR 64            // mem rows per chunk
#define NSLAB 24          // K slabs of 32
#define EPSF 1e-6f
#define NRB 384           // row-block groups (grid = 2 * NRB = 768 = 3 blocks/CU)

typedef short bf16x8 __attribute__((ext_vector_type(8)));
typedef float f32x4 __attribute__((ext_vector_type(4)));

__device__ __forceinline__ unsigned short f2bf(float x) {
  __hip_bfloat16 h = __float2bfloat16(x);
  return __builtin_bit_cast(unsigned short, h);
}

// ---------------- kernel 1: patch row norms ----------------
__global__ __launch_bounds__(256) void k_norm(const float* __restrict__ pf,
                                              float* __restrict__ invn) {
  int row = blockIdx.x;          // 576
  int t = threadIdx.x;
  const float* src = pf + (size_t)row * DD;
  float v0 = src[t], v1 = src[t + 256], v2 = src[t + 512];
  float ss = v0 * v0 + v1 * v1 + v2 * v2;
#pragma unroll
  for (int m = 1; m < 64; m <<= 1) ss += __shfl_xor(ss, m, 64);
  __shared__ float wss[4];
  if ((t & 63) == 0) wss[t >> 6] = ss;
  __syncthreads();
  if (t == 0) {
    float tot = wss[0] + wss[1] + wss[2] + wss[3];
    invn[row] = 1.0f / (sqrtf(tot) + EPSF);
  }
}

// ---------------- kernel 2: pack F into slab-fragment layout ----------------
// Fws[ks][ptg][slot][8] bf16: patch = ptg*16 + (slot&15), k = ks*32 + (slot>>4)*8 + j
__global__ __launch_bounds__(256) void k_pack(const float* __restrict__ pf,
                                              const float* __restrict__ invn,
                                              unsigned short* __restrict__ Fws) {
  int bid = blockIdx.x;          // 864 = 24 ks * 36 ptg
  int ks = bid / 36, ptg = bid % 36;
  int t = threadIdx.x;
  int i = t * 2;                 // short index in region [0,512)
  int s = i >> 3, j = i & 7;
  int p = ptg * 16 + (s & 15);
  int k = ks * 32 + (s >> 4) * 8 + j;
  float sc = invn[p];
  float a0 = pf[(size_t)p * DD + k] * sc;
  float a1 = pf[(size_t)p * DD + k + 1] * sc;
  unsigned int outw = (unsigned int)f2bf(a0) | ((unsigned int)f2bf(a1) << 16);
  ((unsigned int*)Fws)[(size_t)bid * 256 + t] = outw;
}

// pack two float4 (8 fp32) into a uint4 of 8 bf16
#define PACK_BW(bw, u0, u1)                                               \
  bw.x = (unsigned int)f2bf(u0.x) | ((unsigned int)f2bf(u0.y) << 16);     \
  bw.y = (unsigned int)f2bf(u0.z) | ((unsigned int)f2bf(u0.w) << 16);     \
  bw.z = (unsigned int)f2bf(u1.x) | ((unsigned int)f2bf(u1.y) << 16);     \
  bw.w = (unsigned int)f2bf(u1.z) | ((unsigned int)f2bf(u1.w) << 16);

#define SQ8(u0, u1)                                                        \
  (u0.x * u0.x + u0.y * u0.y + u0.z * u0.z + u0.w * u0.w +                 \
   u1.x * u1.x + u1.y * u1.y + u1.z * u1.z + u1.w * u1.w)

// One K-slab step. buf: compile-time LDS buffer holding slab ks.
// I0/I1: register set to ISSUE B(ks+2) into. C0/C1: set holding B(ks+1) to convert.
#define KSTEP(ks, buf, I0, I1, C0, C1)                                     \
  {                                                                        \
    const unsigned short* Ak = Abase + (size_t)(ks) * (36 * 512);          \
    bf16x8 ar[9];                                                          \
    _Pragma("unroll")                                                      \
    for (int p = 0; p < 9; ++p) ar[p] = *(const bf16x8*)(Ak + p * 512);    \
    __builtin_amdgcn_sched_barrier(0); /* keep B issue AFTER A issue */    \
    if ((ks) + 2 < NSLAB) {                                                \
      const float* g = gsrc + ((ks) + 2) * 32;                             \
      I0 = *(const float4*)g;                                              \
      I1 = *(const float4*)(g + 4);                                        \
    }                                                                      \
    bf16x8 b0 = *(const bf16x8*)((const char*)Bs[buf] + rbyte0);           \
    bf16x8 b1 = *(const bf16x8*)((const char*)Bs[buf] + rbyte1);           \
    _Pragma("unroll")                                                      \
    for (int p = 0; p < 9; ++p) {                                          \
      acc[p][0] = __builtin_amdgcn_mfma_f32_16x16x32_bf16(ar[p], b0, acc[p][0], 0, 0, 0); \
      acc[p][1] = __builtin_amdgcn_mfma_f32_16x16x32_bf16(ar[p], b1, acc[p][1], 0, 0, 0); \
    }                                                                      \
    if ((ks) < NSLAB - 1) {                                                \
      ssr += SQ8(C0, C1);                                                  \
      uint4 bw;                                                            \
      PACK_BW(bw, C0, C1);                                                 \
      *(uint4*)((char*)Bs[(buf) ^ 1] + wbyte) = bw;                        \
    }                                                                      \
    __syncthreads();                                                       \
  }

// ---------------- kernel 3: main MFMA kernel ----------------
// 256 threads = 4 waves: pw = w&1 (9 patch-tiles each), rw = w>>1 (2 row-tiles each)
// A-fragments straight from L2-resident Fws (issued FIRST each step);
// B double-buffered in LDS, register-prefetched 2 slabs deep (P/Q sets).
__global__ __launch_bounds__(256, 3) void k_main(const unsigned short* __restrict__ Fws,
                                                 const float* __restrict__ mem,
                                                 float* __restrict__ partial,
                                                 int M, int nchunk) {
  __shared__ __align__(16) unsigned short Bs[2][2048];   // 2 x 4KB bf16 slab
  __shared__ float smin[2][288];
  __shared__ float ssq[BMR];

  int t = threadIdx.x;
  int l = t & 63, l15 = l & 15, lhi = l >> 4;
  int w = t >> 6, pw = w & 1, rw = w >> 1;
  int c = blockIdx.x & 1, rb = blockIdx.x >> 1;
  int srow = t >> 2, sq = t & 3;      // staging: row 0..63, k-seg 0..3

  for (int i = t; i < 2 * 288; i += 256) ((float*)smin)[i] = 1e30f;

  const unsigned short* Abase =
      Fws + (size_t)(c * 18 + pw * 9) * 512 + (size_t)(lhi * 16 + l15) * 8;

  int rbyte0, rbyte1;
  {
    int sw = ((l15 & 7) << 4);
    rbyte0 = (rw * 2 + 0) * 1024 + ((l15 * 64 + lhi * 16) ^ sw);
    rbyte1 = (rw * 2 + 1) * 1024 + ((l15 * 64 + lhi * 16) ^ sw);
  }
  int wl15 = srow & 15;
  int wbyte = (srow >> 4) * 1024 + ((wl15 * 64 + sq * 16) ^ ((wl15 & 7) << 4));

#pragma unroll 1
  for (int chunk = rb; chunk < nchunk; chunk += NRB) {
    int grow = chunk * BMR + srow;
    if (grow > M - 1) grow = M - 1;
    const float* gsrc = mem + (size_t)grow * DD + sq * 8;
    float ssr = 0.f;

    // ---- prologue: P=B(0) -> convert -> Bs[0];  Q=B(1) stays in flight ----
    float4 P0, P1, Q0, Q1;
    P0 = *(const float4*)(gsrc);
    P1 = *(const float4*)(gsrc + 4);
    Q0 = *(const float4*)(gsrc + 32);
    Q1 = *(const float4*)(gsrc + 36);
    ssr += SQ8(P0, P1);
    {
      uint4 bw;
      PACK_BW(bw, P0, P1);
      *(uint4*)((char*)Bs[0] + wbyte) = bw;
    }
    __syncthreads();

    f32x4 acc[9][2];
#pragma unroll
    for (int p = 0; p < 9; ++p) {
      f32x4 z = {0.f, 0.f, 0.f, 0.f};
      acc[p][0] = z;
      acc[p][1] = z;
    }

#pragma unroll 1
    for (int ks = 0; ks < NSLAB; ks += 2) {
      KSTEP(ks, 0, P0, P1, Q0, Q1);       // even: issue B(ks+2)->P, convert Q=B(ks+1)
      KSTEP(ks + 1, 1, Q0, Q1, P0, P1);   // odd:  issue B(ks+3)->Q, convert P=B(ks+2)
    }

    // ---- ssq: reduce over the 4 k-seg threads per row (in-wave) ----
    float s2 = ssr + __shfl_xor(ssr, 1, 64);
    s2 += __shfl_xor(s2, 2, 64);
    if (sq == 0) ssq[srow] = s2;
    __syncthreads();

    // ---- epilogue: dist + min over this chunk's 64 rows ----
    float inv0, inv1;
    bool ok0, ok1;
    {
      int rl0 = (rw * 2 + 0) * 16 + l15;
      int rl1 = (rw * 2 + 1) * 16 + l15;
      inv0 = 1.0f / (sqrtf(ssq[rl0]) + EPSF);
      inv1 = 1.0f / (sqrtf(ssq[rl1]) + EPSF);
      ok0 = (chunk * BMR + rl0) < M;
      ok1 = (chunk * BMR + rl1) < M;
    }
#pragma unroll
    for (int p = 0; p < 9; ++p) {
#pragma unroll
      for (int q = 0; q < 4; ++q) {
        float e0 = ok0 ? (1.0f - acc[p][0][q] * inv0) : 1e30f;
        float e1 = ok1 ? (1.0f - acc[p][1][q] * inv1) : 1e30f;
        float d = fminf(e0, e1);
        d = fminf(d, __shfl_xor(d, 1, 64));
        d = fminf(d, __shfl_xor(d, 2, 64));
        d = fminf(d, __shfl_xor(d, 4, 64));
        d = fminf(d, __shfl_xor(d, 8, 64));
        if (l15 == 0) {
          int pl = (pw * 9 + p) * 16 + lhi * 4 + q;
          smin[rw][pl] = fminf(smin[rw][pl], d);
        }
      }
    }
    __syncthreads();   // smin/ssq settled before next chunk
  }

  for (int i = t; i < 288; i += 256)
    partial[(size_t)rb * NPATCH + c * 288 + i] = fminf(smin[0][i], smin[1][i]);
}

// ---------------- kernel 4: min over partials -> patch_scores ----------------
__global__ __launch_bounds__(256) void k_colmin(const float* __restrict__ partial,
                                                float* __restrict__ out, int nb) {
  int p = blockIdx.x;   // 576
  int t = threadIdx.x;
  float v = 1e30f;
  for (int b = t; b < nb; b += 256) v = fminf(v, partial[(size_t)b * NPATCH + p]);
#pragma unroll
  for (int m = 1; m < 64; m <<= 1) v = fminf(v, __shfl_xor(v, m, 64));
  __shared__ float wmin[4];
  if ((t & 63) == 0) wmin[t >> 6] = v;
  __syncthreads();
  if (t == 0) out[p] = fminf(fminf(wmin[0], wmin[1]), fminf(wmin[2], wmin[3]));
}

// ---------------- kernel 5: top-k mean -> image score ----------------
__global__ __launch_bounds__(256) void k_topk(float* __restrict__ out,
                                              const int* __restrict__ topk_p) {
  __shared__ float vals[NPATCH];
  __shared__ float wv[4];
  __shared__ int wi[4];
  __shared__ float ssum;
  int t = threadIdx.x;
  for (int p = t; p < NPATCH; p += 256) vals[p] = out[p];
  if (t == 0) ssum = 0.f;
  int k = topk_p[0];
  if (k > NPATCH) k = NPATCH;
  if (k < 1) k = 1;
  __syncthreads();
  for (int it = 0; it < k; ++it) {
    float bv = -1e30f;
    int bi = 0;
    for (int p = t; p < NPATCH; p += 256) {
      float x = vals[p];
      if (x > bv) { bv = x; bi = p; }
    }
#pragma unroll
    for (int m = 1; m < 64; m <<= 1) {
      float ov = __shfl_xor(bv, m, 64);
      int oi = __shfl_xor(bi, m, 64);
      if (ov > bv || (ov == bv && oi < bi)) { bv = ov; bi = oi; }
    }
    if ((t & 63) == 0) { wv[t >> 6] = bv; wi[t >> 6] = bi; }
    __syncthreads();
    if (t == 0) {
      float fbv = wv[0]; int fbi = wi[0];
      for (int q = 1; q < 4; ++q)
        if (wv[q] > fbv || (wv[q] == fbv && wi[q] < fbi)) { fbv = wv[q]; fbi = wi[q]; }
      ssum += fbv;
      vals[fbi] = -1e30f;
    }
    __syncthreads();
  }
  if (t == 0) out[NPATCH] = ssum / (float)k;
}

extern "C" void kernel_launch(void* const* d_in, const int* in_sizes, int n_in,
                              void* d_out, int out_size, void* d_ws, size_t ws_size,
                              hipStream_t stream) {
  const float* pf = (const float*)d_in[0];
  const float* mem = (const float*)d_in[1];
  const int* topk = (const int*)d_in[2];
  float* out = (float*)d_out;
  int M = in_sizes[1] / DD;                      // 200000
  int nchunk = (M + BMR - 1) / BMR;              // 3125

  // ws layout: Fws (24*36*512 shorts = 884736B) | invn (576*4) | partial (384*576*4)
  unsigned short* Fws = (unsigned short*)d_ws;
  float* invn = (float*)((char*)d_ws + 884736);
  float* partial = (float*)((char*)d_ws + 884736 + 2304);

  k_norm<<<NPATCH, 256, 0, stream>>>(pf, invn);
  k_pack<<<864, 256, 0, stream>>>(pf, invn, Fws);
  k_main<<<2 * NRB, 256, 0, stream>>>(Fws, mem, partial, M, nchunk);
  k_colmin<<<NPATCH, 256, 0, stream>>>(partial, out, NRB);
  k_topk<<<1, 256, 0, stream>>>(out, topk);
}